// Round 12
// baseline (151.906 us; speedup 1.0000x reference)
//
#include <hip/hip_runtime.h>

typedef _Float16 f16x8 __attribute__((ext_vector_type(8)));
typedef float    f32x16 __attribute__((ext_vector_type(16)));

#define HWSZ   1024
#define DDIM   256
#define KCODES 1024
#define NROWS  65536
#define TAU    0.07f
#define NINF  -3.4e38f

union U16 { uint4 u; f16x8 h; };

__device__ __forceinline__ void gl2lds16(const void* g, void* l) {
    __builtin_amdgcn_global_load_lds(
        (const __attribute__((address_space(1))) unsigned int*)(g),
        (__attribute__((address_space(3))) unsigned int*)(l), 16, 0, 0);
}

// ---------------- e2[k] = sum_d embed[d][k]^2 (also zeroes count) ----------------
__global__ void e2_kernel(const float* __restrict__ embed, float* __restrict__ e2,
                          int* __restrict__ count) {
    int id = blockIdx.x * 256 + threadIdx.x;   // 4096 threads, 4 per code
    if (id == 0) *count = 0;
    int k = id >> 2, q = id & 3;
    float s = 0.f;
#pragma unroll 8
    for (int dd = 0; dd < 64; ++dd) {
        float v = embed[(size_t)(q * 64 + dd) * KCODES + k];
        s = fmaf(v, v, s);
    }
    s += __shfl_xor(s, 1, 64);
    s += __shfl_xor(s, 2, 64);
    if (q == 0) e2[k] = s;
}

// ---------------- prep: fp16(embed), [cc4][ks16][cf8][slot64] x uint4 ----------------
// code = cc*256 + cf*32 + (slot&31); d = ks*16 + (slot>>5)*8 + j
__global__ void prep_e(const float* __restrict__ embed, uint4* __restrict__ ehat) {
    int id = blockIdx.x * 256 + threadIdx.x;   // 32768
    int slot = id & 63;
    int cf   = (id >> 6) & 7;
    int estep = id >> 9;                       // 0..63 = cc*16+ks
    int cc = estep >> 4, ks = estep & 15;
    int code = cc * 256 + cf * 32 + (slot & 31);
    int dbase = ks * 16 + (slot >> 5) * 8;
    _Float16 h[8];
#pragma unroll
    for (int j = 0; j < 8; ++j)
        h[j] = (_Float16)embed[(size_t)(dbase + j) * KCODES + code];
    uint4 o;
    __builtin_memcpy(&o, h, 16);
    ehat[id] = o;
}

// ---------------- transpose: embedT[k][d] = embed[d][k] ----------------
__global__ void transpose_e(const float* __restrict__ embed, float* __restrict__ embedT) {
    int id = blockIdx.x * 256 + threadIdx.x;   // 262144
    int k = id & 1023, d = id >> 10;
    embedT[(size_t)k * 256 + d] = embed[(size_t)d * 1024 + k];   // coalesced reads
}

// ---------------- main: E resident in LDS (128KB), X streamed in 16 tiles ----------------
__global__ __launch_bounds__(512, 2)
void vq_main(const float* __restrict__ x, const uint4* __restrict__ ehat,
             const float* __restrict__ e2,
             float* __restrict__ pm1, float* __restrict__ pm2, int* __restrict__ pidx) {
    __shared__ __align__(16) char smem[163840];
    char* ES = smem;            // 128 KB: [ks16][cf8][slot64] x 16B (this block's cc-chunk)
    char* XS = smem + 131072;   // 32 KB:  [ks16][pf2][kg2][pl32] x 16B

    const int t    = threadIdx.x;
    const int lane = t & 63;
    const int w    = t >> 6;       // 0..7
    const int wr   = w >> 1;       // code quarter within chunk (cf pair)
    const int wc   = w & 1;        // pixel half
    const int kg   = lane >> 5;
    const int l31  = lane & 31;

    const int cc = blockIdx.x & 3;
    const int b  = blockIdx.x >> 2;
    const float* xb = x + (size_t)b * (DDIM * HWSZ);

    // ---- DMA this cc-chunk of E into LDS (once per block) ----
    {
        const char* gs = (const char*)(ehat + (size_t)cc * 8192);
#pragma unroll
        for (int i = 0; i < 16; ++i)
            gl2lds16(gs + (i * 512 + t) * 16, ES + (i * 512 + t) * 16);
    }

    // ---- preload -e2/2 for this wave's fixed 32 codes (per lane) ----
    float e2c[2][16];
#pragma unroll
    for (int cf = 0; cf < 2; ++cf)
#pragma unroll
        for (int r = 0; r < 16; ++r) {
            int code = cc * 256 + (wr * 2 + cf) * 32 + (r & 3) + 8 * (r >> 2) + 4 * kg;
            e2c[cf][r] = -0.5f * e2[code];
        }

    for (int tile = 0; tile < 16; ++tile) {
        // ---- stage X tile (64 px): f32 -> fp16, cached loads (re-read by 4 cc-blocks) ----
        {
            int pix = t & 63, dq = t >> 6;     // dq 0..7
            int pf = pix >> 5, pl = pix & 31;
            const float* xpix = xb + tile * 64 + pix;
#pragma unroll
            for (int uu = 0; uu < 4; ++uu) {
                int unit = uu * 8 + dq;        // d-octet 0..31; ks=unit>>1, kg=unit&1
                int d0 = unit * 8;
                _Float16 h[8];
#pragma unroll
                for (int j = 0; j < 8; ++j)
                    h[j] = (_Float16)xpix[(size_t)(d0 + j) * HWSZ];
                uint4 hv;
                __builtin_memcpy(&hv, h, 16);
                *(uint4*)(XS + ((((unit >> 1) * 4 + pf * 2 + (unit & 1)) * 32 + pl) << 4)) = hv;
            }
        }
        __syncthreads();   // X (and, on tile 0, the E DMA) landed

        f32x16 acc[2];
#pragma unroll
        for (int cf = 0; cf < 2; ++cf)
#pragma unroll
            for (int r = 0; r < 16; ++r)
                acc[cf][r] = e2c[cf][r];

        // ---- K-loop: LDS-only ----
#pragma unroll
        for (int ks = 0; ks < 16; ++ks) {
            U16 a0, a1;
            a0.u = *(const uint4*)(ES + (((ks * 8 + wr * 2 + 0) * 64 + lane) << 4));
            a1.u = *(const uint4*)(ES + (((ks * 8 + wr * 2 + 1) * 64 + lane) << 4));
            f16x8 B = *(const f16x8*)(XS + (((ks * 4 + wc * 2 + kg) * 32 + l31) << 4));
            acc[0] = __builtin_amdgcn_mfma_f32_32x32x16_f16(a0.h, B, acc[0], 0, 0, 0);
            acc[1] = __builtin_amdgcn_mfma_f32_32x32x16_f16(a1.h, B, acc[1], 0, 0, 0);
        }

        // ---- per-lane top-2 over 32 codes (ascending scan order), kg merge ----
        float m1 = NINF, m2 = NINF; int idx = 0x7FFFFFFF;
#pragma unroll
        for (int cf = 0; cf < 2; ++cf)
#pragma unroll
            for (int r = 0; r < 16; ++r) {
                float v = acc[cf][r];
                int code = cc * 256 + (wr * 2 + cf) * 32 + (r & 3) + 8 * (r >> 2) + 4 * kg;
                bool gt = v > m1;
                m2 = fmaxf(m2, fminf(v, m1));
                m1 = fmaxf(m1, v);
                idx = gt ? code : idx;
            }
        {
            float om1 = __shfl_xor(m1, 32, 64);
            float om2 = __shfl_xor(m2, 32, 64);
            int   oid = __shfl_xor(idx, 32, 64);
            float nm2 = fmaxf(fmaxf(m2, om2), fminf(m1, om1));
            bool tk = (om1 > m1) || (om1 == m1 && oid < idx);
            m1 = tk ? om1 : m1; idx = tk ? oid : idx; m2 = nm2;
        }

        // ---- cross-wr merge (overlay scratch on XS; K-loop reads are done) ----
        __syncthreads();
        float* sv = (float*)XS;          // [64][4]
        float* sw = (float*)(XS + 1024);
        int*   si = (int*)(XS + 2048);
        if (lane < 32) {
            int px = wc * 32 + l31;
            sv[px * 4 + wr] = m1;
            sw[px * 4 + wr] = m2;
            si[px * 4 + wr] = idx;
        }
        __syncthreads();
        if (t < 64) {
            float V1 = NINF, V2 = NINF; int I1 = 0x7FFFFFFF;
#pragma unroll
            for (int q = 0; q < 4; ++q) {
                float a1v = sv[t * 4 + q], a2v = sw[t * 4 + q]; int ai = si[t * 4 + q];
                float m2n = fmaxf(fmaxf(V2, a2v), fminf(V1, a1v));
                bool tk = (a1v > V1) || (a1v == V1 && ai < I1);
                V1 = tk ? a1v : V1; I1 = tk ? ai : I1; V2 = m2n;
            }
            int gp = b * 1024 + tile * 64 + t;
            pm1[(size_t)cc * NROWS + gp] = V1;
            pm2[(size_t)cc * NROWS + gp] = V2;
            pidx[(size_t)cc * NROWS + gp] = I1;
        }
        __syncthreads();   // scratch free before next tile's X stage
    }
}

// ---------------- merge 4 cc-partials -> ind + flagged list ----------------
__global__ void merge_kernel(const float* __restrict__ pm1, const float* __restrict__ pm2,
                             const int* __restrict__ pidx,
                             int* __restrict__ ind, int* __restrict__ count,
                             int* __restrict__ list) {
    int pix = blockIdx.x * 256 + threadIdx.x;
    float V1 = NINF, V2 = NINF; int I1 = 0x7FFFFFFF;
#pragma unroll
    for (int cc = 0; cc < 4; ++cc) {
        float a1 = pm1[(size_t)cc * NROWS + pix];
        float a2 = pm2[(size_t)cc * NROWS + pix];
        int   ai = pidx[(size_t)cc * NROWS + pix];
        float m2n = fmaxf(fmaxf(V2, a2), fminf(V1, a1));
        bool tk = (a1 > V1) || (a1 == V1 && ai < I1);
        V1 = tk ? a1 : V1; I1 = tk ? ai : I1; V2 = m2n;
    }
    ind[pix] = I1;
    if (V1 - V2 < TAU) {
        int pos = atomicAdd(count, 1);
        list[pos] = pix;
    }
}

// ---------------- fixup: exact f32 re-argmin -> corrects ind (before gather) ----------------
__global__ __launch_bounds__(256)
void fixup_kernel(const float* __restrict__ x, const float* __restrict__ embed,
                  const float* __restrict__ e2, int* __restrict__ ind,
                  const int* __restrict__ count, const int* __restrict__ list) {
    __shared__ float XL[8][DDIM];
    __shared__ float cv[8][4];
    __shared__ int   ci[8][4];
    const int t = threadIdx.x;
    const int nf = *count;
    for (int base = blockIdx.x * 8; base < nf; base += gridDim.x * 8) {
        int m = min(8, nf - base);
        {
            int p = t >> 5, idx = t & 31;
            if (p < m) {
                int pix = list[base + p];
                int b = pix >> 10, hw = pix & 1023;
                const float* xr = x + (size_t)b * (DDIM * HWSZ) + hw;
#pragma unroll
                for (int j = 0; j < 8; ++j) {
                    int d = idx * 8 + j;
                    XL[p][d] = xr[(size_t)d * HWSZ];
                }
            }
        }
        __syncthreads();
        const int c0 = t * 4;
        float4 a[8];
#pragma unroll
        for (int p = 0; p < 8; ++p) a[p] = make_float4(0.f, 0.f, 0.f, 0.f);
        for (int d4 = 0; d4 < DDIM; d4 += 4) {
            float4 ev0 = *(const float4*)&embed[(size_t)(d4 + 0) * KCODES + c0];
            float4 ev1 = *(const float4*)&embed[(size_t)(d4 + 1) * KCODES + c0];
            float4 ev2 = *(const float4*)&embed[(size_t)(d4 + 2) * KCODES + c0];
            float4 ev3 = *(const float4*)&embed[(size_t)(d4 + 3) * KCODES + c0];
#pragma unroll
            for (int p = 0; p < 8; ++p) {
                float4 xq = *(const float4*)&XL[p][d4];
                a[p].x = fmaf(xq.x, ev0.x, a[p].x); a[p].y = fmaf(xq.x, ev0.y, a[p].y);
                a[p].z = fmaf(xq.x, ev0.z, a[p].z); a[p].w = fmaf(xq.x, ev0.w, a[p].w);
                a[p].x = fmaf(xq.y, ev1.x, a[p].x); a[p].y = fmaf(xq.y, ev1.y, a[p].y);
                a[p].z = fmaf(xq.y, ev1.z, a[p].z); a[p].w = fmaf(xq.y, ev1.w, a[p].w);
                a[p].x = fmaf(xq.z, ev2.x, a[p].x); a[p].y = fmaf(xq.z, ev2.y, a[p].y);
                a[p].z = fmaf(xq.z, ev2.z, a[p].z); a[p].w = fmaf(xq.z, ev2.w, a[p].w);
                a[p].x = fmaf(xq.w, ev3.x, a[p].x); a[p].y = fmaf(xq.w, ev3.y, a[p].y);
                a[p].z = fmaf(xq.w, ev3.z, a[p].z); a[p].w = fmaf(xq.w, ev3.w, a[p].w);
            }
        }
        float4 e2q = *(const float4*)&e2[c0];
#pragma unroll
        for (int p = 0; p < 8; ++p) {
            float bv = e2q.x - 2.f * a[p].x; int bi = c0;
            float d1 = e2q.y - 2.f * a[p].y; if (d1 < bv) { bv = d1; bi = c0 + 1; }
            float d2 = e2q.z - 2.f * a[p].z; if (d2 < bv) { bv = d2; bi = c0 + 2; }
            float d3 = e2q.w - 2.f * a[p].w; if (d3 < bv) { bv = d3; bi = c0 + 3; }
#pragma unroll
            for (int mm = 1; mm <= 32; mm <<= 1) {
                float ov = __shfl_xor(bv, mm, 64);
                int   oi = __shfl_xor(bi, mm, 64);
                if (ov < bv || (ov == bv && oi < bi)) { bv = ov; bi = oi; }
            }
            if ((t & 63) == 0) { cv[p][t >> 6] = bv; ci[p][t >> 6] = bi; }
        }
        __syncthreads();
        if (t < m) {
            float V = cv[t][0]; int I = ci[t][0];
#pragma unroll
            for (int q = 1; q < 4; ++q)
                if (cv[t][q] < V || (cv[t][q] == V && ci[t][q] < I)) { V = cv[t][q]; I = ci[t][q]; }
            ind[list[base + t]] = I;
        }
        __syncthreads();
    }
}

// ---------------- gather: 1 px x 4 d per thread; contiguous 16B gather reads ----------------
__global__ void gather_kernel(const float4* __restrict__ embedT4, const int* __restrict__ ind,
                              float* __restrict__ out) {
    unsigned tid = blockIdx.x * 256u + threadIdx.x;   // 4M threads
    unsigned hw = tid & 1023u;
    unsigned r  = tid >> 10;           // b*64 + dq
    unsigned dq = r & 63u, b = r >> 6;
    int idx = ind[(b << 10) + hw];
    float4 e = embedT4[(size_t)idx * 64 + dq];
    size_t o = (((size_t)(b * 256 + dq * 4)) << 10) + hw;
    out[o]        = e.x;
    out[o + 1024] = e.y;
    out[o + 2048] = e.z;
    out[o + 3072] = e.w;
    size_t o2 = o + (1u << 24);
    out[o2]        = e.x;
    out[o2 + 1024] = e.y;
    out[o2 + 2048] = e.z;
    out[o2 + 3072] = e.w;
}

extern "C" void kernel_launch(void* const* d_in, const int* in_sizes, int n_in,
                              void* d_out, int out_size, void* d_ws, size_t ws_size,
                              hipStream_t stream) {
    const float* x     = (const float*)d_in[0];
    const float* embed = (const float*)d_in[1];
    float* out = (float*)d_out;
    char* ws = (char*)d_ws;

    int*    ind    = (int*)ws;                          // 262144 B
    float*  e2     = (float*)(ws + 262144);             // 4096 B
    uint4*  ehat   = (uint4*)(ws + 266240);             // 524288 B
    float*  embedT = (float*)(ws + 790528);             // 1048576 B
    float*  pm1    = (float*)(ws + 1839104);            // 1048576 B
    float*  pm2    = (float*)(ws + 2887680);            // 1048576 B
    int*    pidx   = (int*)(ws + 3936256);              // 1048576 B
    int*    count  = (int*)(ws + 4984832);              // 4 B
    int*    list   = (int*)(ws + 4984836);              // up to 256 KiB

    e2_kernel<<<16, 256, 0, stream>>>(embed, e2, count);
    prep_e<<<128, 256, 0, stream>>>(embed, ehat);
    transpose_e<<<1024, 256, 0, stream>>>(embed, embedT);
    vq_main<<<256, 512, 0, stream>>>(x, ehat, e2, pm1, pm2, pidx);
    merge_kernel<<<NROWS / 256, 256, 0, stream>>>(pm1, pm2, pidx, ind, count, list);
    fixup_kernel<<<320, 256, 0, stream>>>(x, embed, e2, ind, count, list);
    gather_kernel<<<(NROWS / 256) * 64, 256, 0, stream>>>((const float4*)embedT, ind, out);
}

// Round 13
// 146.124 us; speedup vs baseline: 1.0396x; 1.0396x over previous
//
#include <hip/hip_runtime.h>

typedef _Float16 f16x8 __attribute__((ext_vector_type(8)));
typedef float    f32x16 __attribute__((ext_vector_type(16)));

#define HWSZ   1024
#define DDIM   256
#define KCODES 1024
#define NROWS  65536
#define TAU    0.07f
#define NINF  -3.4e38f

union U16 { uint4 u; f16x8 h; };

__device__ __forceinline__ void gl2lds16(const void* g, void* l) {
    __builtin_amdgcn_global_load_lds(
        (const __attribute__((address_space(1))) unsigned int*)(g),
        (__attribute__((address_space(3))) unsigned int*)(l), 16, 0, 0);
}

// ---------------- e2[k] = sum_d embed[d][k]^2 (also zeroes count) ----------------
__global__ void e2_kernel(const float* __restrict__ embed, float* __restrict__ e2,
                          int* __restrict__ count) {
    int id = blockIdx.x * 256 + threadIdx.x;
    if (id == 0) *count = 0;
    int k = id >> 2, q = id & 3;
    float s = 0.f;
#pragma unroll 8
    for (int dd = 0; dd < 64; ++dd) {
        float v = embed[(size_t)(q * 64 + dd) * KCODES + k];
        s = fmaf(v, v, s);
    }
    s += __shfl_xor(s, 1, 64);
    s += __shfl_xor(s, 2, 64);
    if (q == 0) e2[k] = s;
}

// ---------------- prep_e: fp16(embed), [cc4][ks16][cf8][slot64] x uint4 ----------------
// code = cc*256 + cf*32 + (slot&31); d = ks*16 + (slot>>5)*8 + j
__global__ void prep_e(const float* __restrict__ embed, uint4* __restrict__ ehat) {
    int id = blockIdx.x * 256 + threadIdx.x;   // 32768
    int slot = id & 63;
    int cf   = (id >> 6) & 7;
    int estep = id >> 9;                       // cc*16+ks
    int cc = estep >> 4, ks = estep & 15;
    int code = cc * 256 + cf * 32 + (slot & 31);
    int dbase = ks * 16 + (slot >> 5) * 8;
    _Float16 h[8];
#pragma unroll
    for (int j = 0; j < 8; ++j)
        h[j] = (_Float16)embed[(size_t)(dbase + j) * KCODES + code];
    uint4 o;
    __builtin_memcpy(&o, h, 16);
    ehat[id] = o;
}

// ---------------- prep_x: fp16(x) in B-frag layout [g2048][ks16][kg2][pl32] x uint4 ----------------
__global__ void prep_x(const float* __restrict__ x, uint4* __restrict__ xhat) {
    int id = blockIdx.x * 256 + threadIdx.x;   // 2,097,152
    int pl = id & 31;
    int kg = (id >> 5) & 1;
    int ks = (id >> 6) & 15;
    int g  = id >> 10;                         // 0..2047
    int px = g * 32 + pl;
    int b = px >> 10, hw = px & 1023;
    const float* xr = x + ((size_t)b * DDIM + ks * 16 + kg * 8) * HWSZ + hw;
    _Float16 h[8];
#pragma unroll
    for (int j = 0; j < 8; ++j)
        h[j] = (_Float16)xr[(size_t)j * HWSZ];
    uint4 o;
    __builtin_memcpy(&o, h, 16);
    xhat[id] = o;
}

// ---------------- transpose: embedT[k][d] = embed[d][k] ----------------
__global__ void transpose_e(const float* __restrict__ embed, float* __restrict__ embedT) {
    int id = blockIdx.x * 256 + threadIdx.x;
    int k = id & 1023, d = id >> 10;
    embedT[(size_t)k * 256 + d] = embed[(size_t)d * 1024 + k];
}

// ---------------- main: A-frags in 128 VGPRs, LDS carries only B, triple-buffered X DMA ----------------
__global__ __launch_bounds__(256, 2)
void vq_main(const uint4* __restrict__ xhat, const uint4* __restrict__ ehat,
             const float* __restrict__ e2,
             float* __restrict__ pm1, float* __restrict__ pm2, int* __restrict__ pidx) {
    __shared__ __align__(16) char smem[51200];   // 3 x 16KB X bufs + 2KB merge scratch
    char* XB = smem;
    char* SC = smem + 49152;

    const int t    = threadIdx.x;
    const int lane = t & 63;
    const int w    = t >> 6;        // 0..3: code sub-quarter
    const int kg   = lane >> 5;
    const int l31  = lane & 31;

    const int cc = blockIdx.x & 3;
    const int pg = blockIdx.x >> 2;              // 0..127
    const int px0 = pg * 512;                    // 16 tiles x 32 px

    // ---- load A-fragments for this wave's 64 codes, all 16 k-steps (128 VGPR) ----
    f16x8 A0[16], A1[16];
#pragma unroll
    for (int ks = 0; ks < 16; ++ks) {
        U16 u0, u1;
        u0.u = ehat[(size_t)(((cc * 16 + ks) * 8) + w * 2 + 0) * 64 + lane];
        u1.u = ehat[(size_t)(((cc * 16 + ks) * 8) + w * 2 + 1) * 64 + lane];
        A0[ks] = u0.h;
        A1[ks] = u1.h;
    }
    // ---- -e2/2 per owned code ----
    float e2c[2][16];
#pragma unroll
    for (int cf = 0; cf < 2; ++cf)
#pragma unroll
        for (int r = 0; r < 16; ++r) {
            int code = cc * 256 + (w * 2 + cf) * 32 + (r & 3) + 8 * (r >> 2) + 4 * kg;
            e2c[cf][r] = -0.5f * e2[code];
        }
    asm volatile("s_waitcnt vmcnt(0)" ::: "memory");   // A,e2 loaded; vmcnt now tracks DMAs only

    // ---- prologue: DMA tiles 0,1 ----
    {
        const uint4* src = xhat + (size_t)(pg * 16) * 1024;
#pragma unroll
        for (int i = 0; i < 4; ++i)
            gl2lds16(src + w * 256 + i * 64 + lane, XB + ((w * 256 + i * 64 + lane) << 4));
#pragma unroll
        for (int i = 0; i < 4; ++i)
            gl2lds16(src + 1024 + w * 256 + i * 64 + lane, XB + 16384 + ((w * 256 + i * 64 + lane) << 4));
    }

    for (int tile = 0; tile < 16; ++tile) {
        if (tile < 15)
            asm volatile("s_waitcnt vmcnt(4)" ::: "memory");   // tile's 4 DMAs landed
        else
            asm volatile("s_waitcnt vmcnt(0)" ::: "memory");
        __syncthreads();
        // issue DMA for tile+2 (safe: all waves done reading that buffer)
        if (tile + 2 < 16) {
            const uint4* src = xhat + (size_t)(pg * 16 + tile + 2) * 1024;
            char* dst = XB + ((tile + 2) % 3) * 16384;
#pragma unroll
            for (int i = 0; i < 4; ++i)
                gl2lds16(src + w * 256 + i * 64 + lane, dst + ((w * 256 + i * 64 + lane) << 4));
        }

        const char* xb = XB + (tile % 3) * 16384;
        f32x16 acc0, acc1;
#pragma unroll
        for (int r = 0; r < 16; ++r) { acc0[r] = e2c[0][r]; acc1[r] = e2c[1][r]; }

#pragma unroll
        for (int ks = 0; ks < 16; ++ks) {
            f16x8 B = *(const f16x8*)(xb + (((ks * 2 + kg) * 32 + l31) << 4));
            acc0 = __builtin_amdgcn_mfma_f32_32x32x16_f16(A0[ks], B, acc0, 0, 0, 0);
            acc1 = __builtin_amdgcn_mfma_f32_32x32x16_f16(A1[ks], B, acc1, 0, 0, 0);
        }

        // ---- per-lane top-2 over 32 codes (monotonic scan), then kg-merge ----
        float m1 = NINF, m2 = NINF; int idx = 0x7FFFFFFF;
#pragma unroll
        for (int r = 0; r < 16; ++r) {
            float v = acc0[r];
            int code = cc * 256 + (w * 2) * 32 + (r & 3) + 8 * (r >> 2) + 4 * kg;
            bool gt = v > m1;
            m2 = fmaxf(m2, fminf(v, m1));
            m1 = fmaxf(m1, v);
            idx = gt ? code : idx;
        }
#pragma unroll
        for (int r = 0; r < 16; ++r) {
            float v = acc1[r];
            int code = cc * 256 + (w * 2 + 1) * 32 + (r & 3) + 8 * (r >> 2) + 4 * kg;
            bool gt = v > m1;
            m2 = fmaxf(m2, fminf(v, m1));
            m1 = fmaxf(m1, v);
            idx = gt ? code : idx;
        }
        {
            float om1 = __shfl_xor(m1, 32, 64);
            float om2 = __shfl_xor(m2, 32, 64);
            int   oid = __shfl_xor(idx, 32, 64);
            float nm2 = fmaxf(fmaxf(m2, om2), fminf(m1, om1));
            bool tk = (om1 > m1) || (om1 == m1 && oid < idx);
            m1 = tk ? om1 : m1; idx = tk ? oid : idx; m2 = nm2;
        }

        // ---- cross-wave merge via scratch ----
        float* sv = (float*)SC;           // [32][4]
        float* sw = (float*)(SC + 512);
        int*   si = (int*)(SC + 1024);
        if (lane < 32) {
            sv[l31 * 4 + w] = m1;
            sw[l31 * 4 + w] = m2;
            si[l31 * 4 + w] = idx;
        }
        __syncthreads();
        if (t < 32) {
            float V1 = NINF, V2 = NINF; int I1 = 0x7FFFFFFF;
#pragma unroll
            for (int q = 0; q < 4; ++q) {
                float a1 = sv[t * 4 + q], a2 = sw[t * 4 + q]; int ai = si[t * 4 + q];
                float m2n = fmaxf(fmaxf(V2, a2), fminf(V1, a1));
                bool tk = (a1 > V1) || (a1 == V1 && ai < I1);
                V1 = tk ? a1 : V1; I1 = tk ? ai : I1; V2 = m2n;
            }
            int gp = px0 + tile * 32 + t;
            pm1[(size_t)cc * NROWS + gp] = V1;
            pm2[(size_t)cc * NROWS + gp] = V2;
            pidx[(size_t)cc * NROWS + gp] = I1;
        }
        // next scratch write is gated by next tile's first barrier
    }
}

// ---------------- merge 4 cc-partials -> ind + flagged list ----------------
__global__ void merge_kernel(const float* __restrict__ pm1, const float* __restrict__ pm2,
                             const int* __restrict__ pidx,
                             int* __restrict__ ind, int* __restrict__ count,
                             int* __restrict__ list) {
    int pix = blockIdx.x * 256 + threadIdx.x;
    float V1 = NINF, V2 = NINF; int I1 = 0x7FFFFFFF;
#pragma unroll
    for (int cc = 0; cc < 4; ++cc) {
        float a1 = pm1[(size_t)cc * NROWS + pix];
        float a2 = pm2[(size_t)cc * NROWS + pix];
        int   ai = pidx[(size_t)cc * NROWS + pix];
        float m2n = fmaxf(fmaxf(V2, a2), fminf(V1, a1));
        bool tk = (a1 > V1) || (a1 == V1 && ai < I1);
        V1 = tk ? a1 : V1; I1 = tk ? ai : I1; V2 = m2n;
    }
    ind[pix] = I1;
    if (V1 - V2 < TAU) {
        int pos = atomicAdd(count, 1);
        list[pos] = pix;
    }
}

// ---------------- fixup: exact f32 re-argmin -> corrects ind ----------------
__global__ __launch_bounds__(256)
void fixup_kernel(const float* __restrict__ x, const float* __restrict__ embed,
                  const float* __restrict__ e2, int* __restrict__ ind,
                  const int* __restrict__ count, const int* __restrict__ list) {
    __shared__ float XL[8][DDIM];
    __shared__ float cv[8][4];
    __shared__ int   ci[8][4];
    const int t = threadIdx.x;
    const int nf = *count;
    for (int base = blockIdx.x * 8; base < nf; base += gridDim.x * 8) {
        int m = min(8, nf - base);
        {
            int p = t >> 5, idx = t & 31;
            if (p < m) {
                int pix = list[base + p];
                int b = pix >> 10, hw = pix & 1023;
                const float* xr = x + (size_t)b * (DDIM * HWSZ) + hw;
#pragma unroll
                for (int j = 0; j < 8; ++j) {
                    int d = idx * 8 + j;
                    XL[p][d] = xr[(size_t)d * HWSZ];
                }
            }
        }
        __syncthreads();
        const int c0 = t * 4;
        float4 a[8];
#pragma unroll
        for (int p = 0; p < 8; ++p) a[p] = make_float4(0.f, 0.f, 0.f, 0.f);
        for (int d4 = 0; d4 < DDIM; d4 += 4) {
            float4 ev0 = *(const float4*)&embed[(size_t)(d4 + 0) * KCODES + c0];
            float4 ev1 = *(const float4*)&embed[(size_t)(d4 + 1) * KCODES + c0];
            float4 ev2 = *(const float4*)&embed[(size_t)(d4 + 2) * KCODES + c0];
            float4 ev3 = *(const float4*)&embed[(size_t)(d4 + 3) * KCODES + c0];
#pragma unroll
            for (int p = 0; p < 8; ++p) {
                float4 xq = *(const float4*)&XL[p][d4];
                a[p].x = fmaf(xq.x, ev0.x, a[p].x); a[p].y = fmaf(xq.x, ev0.y, a[p].y);
                a[p].z = fmaf(xq.x, ev0.z, a[p].z); a[p].w = fmaf(xq.x, ev0.w, a[p].w);
                a[p].x = fmaf(xq.y, ev1.x, a[p].x); a[p].y = fmaf(xq.y, ev1.y, a[p].y);
                a[p].z = fmaf(xq.y, ev1.z, a[p].z); a[p].w = fmaf(xq.y, ev1.w, a[p].w);
                a[p].x = fmaf(xq.z, ev2.x, a[p].x); a[p].y = fmaf(xq.z, ev2.y, a[p].y);
                a[p].z = fmaf(xq.z, ev2.z, a[p].z); a[p].w = fmaf(xq.z, ev2.w, a[p].w);
                a[p].x = fmaf(xq.w, ev3.x, a[p].x); a[p].y = fmaf(xq.w, ev3.y, a[p].y);
                a[p].z = fmaf(xq.w, ev3.z, a[p].z); a[p].w = fmaf(xq.w, ev3.w, a[p].w);
            }
        }
        float4 e2q = *(const float4*)&e2[c0];
#pragma unroll
        for (int p = 0; p < 8; ++p) {
            float bv = e2q.x - 2.f * a[p].x; int bi = c0;
            float d1 = e2q.y - 2.f * a[p].y; if (d1 < bv) { bv = d1; bi = c0 + 1; }
            float d2 = e2q.z - 2.f * a[p].z; if (d2 < bv) { bv = d2; bi = c0 + 2; }
            float d3 = e2q.w - 2.f * a[p].w; if (d3 < bv) { bv = d3; bi = c0 + 3; }
#pragma unroll
            for (int mm = 1; mm <= 32; mm <<= 1) {
                float ov = __shfl_xor(bv, mm, 64);
                int   oi = __shfl_xor(bi, mm, 64);
                if (ov < bv || (ov == bv && oi < bi)) { bv = ov; bi = oi; }
            }
            if ((t & 63) == 0) { cv[p][t >> 6] = bv; ci[p][t >> 6] = bi; }
        }
        __syncthreads();
        if (t < m) {
            float V = cv[t][0]; int I = ci[t][0];
#pragma unroll
            for (int q = 1; q < 4; ++q)
                if (cv[t][q] < V || (cv[t][q] == V && ci[t][q] < I)) { V = cv[t][q]; I = ci[t][q]; }
            ind[list[base + t]] = I;
        }
        __syncthreads();
    }
}

// ---------------- gather: 1 px x 4 d per thread; contiguous 16B gather reads ----------------
__global__ void gather_kernel(const float4* __restrict__ embedT4, const int* __restrict__ ind,
                              float* __restrict__ out) {
    unsigned tid = blockIdx.x * 256u + threadIdx.x;
    unsigned hw = tid & 1023u;
    unsigned r  = tid >> 10;
    unsigned dq = r & 63u, b = r >> 6;
    int idx = ind[(b << 10) + hw];
    float4 e = embedT4[(size_t)idx * 64 + dq];
    size_t o = (((size_t)(b * 256 + dq * 4)) << 10) + hw;
    out[o]        = e.x;
    out[o + 1024] = e.y;
    out[o + 2048] = e.z;
    out[o + 3072] = e.w;
    size_t o2 = o + (1u << 24);
    out[o2]        = e.x;
    out[o2 + 1024] = e.y;
    out[o2 + 2048] = e.z;
    out[o2 + 3072] = e.w;
}

extern "C" void kernel_launch(void* const* d_in, const int* in_sizes, int n_in,
                              void* d_out, int out_size, void* d_ws, size_t ws_size,
                              hipStream_t stream) {
    const float* x     = (const float*)d_in[0];
    const float* embed = (const float*)d_in[1];
    float* out = (float*)d_out;
    char* ws = (char*)d_ws;

    int*    ind    = (int*)ws;                          // 262144 B
    float*  e2     = (float*)(ws + 262144);             // 4096 B
    uint4*  ehat   = (uint4*)(ws + 266240);             // 524288 B
    float*  embedT = (float*)(ws + 790528);             // 1048576 B
    float*  pm1    = (float*)(ws + 1839104);            // 1048576 B
    float*  pm2    = (float*)(ws + 2887680);            // 1048576 B
    int*    pidx   = (int*)(ws + 3936256);              // 1048576 B
    int*    count  = (int*)(ws + 4984832);              // 4 B
    int*    list   = (int*)(ws + 4984836);              // up to 256 KiB

    // xhat (32 MB) lives in the FRONT of d_out; vq_main finishes before gather overwrites it
    uint4*  xhat   = (uint4*)d_out;

    e2_kernel<<<16, 256, 0, stream>>>(embed, e2, count);
    prep_e<<<128, 256, 0, stream>>>(embed, ehat);
    prep_x<<<8192, 256, 0, stream>>>(x, xhat);
    transpose_e<<<1024, 256, 0, stream>>>(embed, embedT);
    vq_main<<<512, 256, 0, stream>>>(xhat, ehat, e2, pm1, pm2, pidx);
    merge_kernel<<<NROWS / 256, 256, 0, stream>>>(pm1, pm2, pidx, ind, count, list);
    fixup_kernel<<<320, 256, 0, stream>>>(x, embed, e2, ind, count, list);
    gather_kernel<<<(NROWS / 256) * 64, 256, 0, stream>>>((const float4*)embedT, ind, out);
}